// Round 1
// baseline (38115.598 us; speedup 1.0000x reference)
//
#include <hip/hip_runtime.h>
#include <hip/hip_cooperative_groups.h>
#include <cmath>

namespace cg = cooperative_groups;

#define Bsz 128
#define Ssz 512
#define Isz 512
#define Hsz 1024
#define G4  4096
#define Ktot 1536   // I + H

typedef short s8v __attribute__((ext_vector_type(8)));        // 8 bf16 (4 VGPRs)
typedef unsigned short u16x8 __attribute__((ext_vector_type(8)));
typedef float f32x16 __attribute__((ext_vector_type(16)));

__device__ __forceinline__ unsigned short f2bf(float f) {
    unsigned u = __float_as_uint(f);
    u += 0x7fffu + ((u >> 16) & 1u);
    return (unsigned short)(u >> 16);
}
__device__ __forceinline__ float bf2f(unsigned short h) {
    return __uint_as_float(((unsigned)h) << 16);
}
__device__ __forceinline__ float fsig(float v) { return 1.f / (1.f + __expf(-v)); }
__device__ __forceinline__ float ftanh(float v) { return 2.f / (1.f + __expf(-2.f * v)) - 1.f; }

// ---- once per call: W,U -> transposed bf16 hi/lo planes WUt[n][k], k<512 = W, k>=512 = U
__global__ __launch_bounds__(256) void conv_wu(const float* __restrict__ W,
                                               const float* __restrict__ U,
                                               unsigned short* __restrict__ WUthi,
                                               unsigned short* __restrict__ WUtlo) {
    __shared__ float tile[32][33];
    const int tx = threadIdx.x & 31, ty = threadIdx.x >> 5;
    const int nb = blockIdx.x * 32, kb = blockIdx.y * 32;
    #pragma unroll
    for (int r = 0; r < 4; ++r) {
        int k = kb + ty + r * 8;
        float v = (k < Isz) ? W[(size_t)k * G4 + nb + tx]
                            : U[(size_t)(k - Isz) * G4 + nb + tx];
        tile[ty + r * 8][tx] = v;
    }
    __syncthreads();
    #pragma unroll
    for (int r = 0; r < 4; ++r) {
        int nl = ty + r * 8;
        float v = tile[tx][nl];
        unsigned short h = f2bf(v);
        size_t dst = (size_t)(nb + nl) * Ktot + kb + tx;
        WUthi[dst] = h;
        WUtlo[dst] = f2bf(v - bf2f(h));
    }
}

// ---- persistent cooperative kernel: init + 512 steps + finalize, one launch
#define PITCH 72          // 64 k + 8 pad (u16 elems); 144 B, 16B-aligned
#define A_HI 0
#define A_LO (128 * PITCH)
#define B_HI (2 * 128 * PITCH)
#define B_LO (2 * 128 * PITCH + 64 * PITCH)
#define SMEM_ELEMS (2 * 128 * PITCH + 2 * 64 * PITCH)   // 27648 u16 = 55296 B

__global__ __launch_bounds__(512, 2) void lstm_persist(
    const unsigned short* __restrict__ WUthi, const unsigned short* __restrict__ WUtlo,
    const float* __restrict__ x, const float* __restrict__ bias,
    float* __restrict__ P,
    unsigned short* __restrict__ hhi, unsigned short* __restrict__ hlo,
    unsigned short* __restrict__ xthi, unsigned short* __restrict__ xtlo,
    float* __restrict__ out) {
    cg::grid_group grid = cg::this_grid();
    extern __shared__ unsigned short sm[];
    unsigned short* sAhi = sm + A_HI;
    unsigned short* sAlo = sm + A_LO;
    unsigned short* sBhi = sm + B_HI;
    unsigned short* sBlo = sm + B_LO;

    const int tid = threadIdx.x, lane = tid & 63, w = tid >> 6;
    const int bid = blockIdx.x;
    const int n0 = (bid & 63) * 64, kt = bid >> 6;

    // wave -> one 32x32 output tile: mq = M-tile (32 rows), nh = N-half (32 cols)
    const int m31  = lane & 31;
    const int koct = (lane >> 5) << 3;                 // 0 or 8
    const int mq = w & 3, nh = w >> 2;
    const int rowA = (mq * 32 + m31) * PITCH + koct;
    const int rowB = (nh * 32 + m31) * PITCH + koct;

    // pointwise ownership: this thread owns (b,j) = idx forever -> c, hsum live in regs
    const int idx = bid * 512 + tid;                   // 0..131071
    const int pb = idx >> 10, pj = idx & 1023;
    float c_reg = 0.f, hs_reg = 0.f;
    const float bf_ = bias[pj], bi_ = bias[1024 + pj],
                bg_ = bias[2048 + pj], bo_ = bias[3072 + pj];

    // init: h = 0, stage x[:, 0, :]
    hhi[idx] = 0; hlo[idx] = 0;
    if (idx < Bsz * Isz) {
        int bb = idx >> 9, ii = idx & 511;
        float xv = x[(size_t)bb * Ssz * Isz + ii];     // t = 0
        unsigned short h = f2bf(xv);
        xthi[idx] = h; xtlo[idx] = f2bf(xv - bf2f(h));
    }
    grid.sync();

    for (int t = 0; t < Ssz; ++t) {
        // ---- gates phase: P[kt][m][n] partial GEMM ----
        f32x16 acc;
        #pragma unroll
        for (int i = 0; i < 16; ++i) acc[i] = 0.f;

        for (int kc = 0; kc < 6; ++kc) {               // 6 chunks of K=64
            const int kbase = kt * 384 + kc * 64;
            const bool isX = (kbase < Isz);            // chunk never straddles k=512
            // A: 128 rows x 8 octets = 1024 slots -> 2/thread (hi & lo)
            #pragma unroll
            for (int i = 0; i < 2; ++i) {
                int q = i * 512 + tid;
                int row = q >> 3, oct = q & 7;
                int kg = kbase + oct * 8;
                const unsigned short* shi;
                const unsigned short* slo;
                if (isX) { shi = xthi + row * Isz + kg;          slo = xtlo + row * Isz + kg; }
                else     { shi = hhi + row * Hsz + (kg - Isz);   slo = hlo + row * Hsz + (kg - Isz); }
                *(u16x8*)&sAhi[row * PITCH + oct * 8] = *(const u16x8*)shi;
                *(u16x8*)&sAlo[row * PITCH + oct * 8] = *(const u16x8*)slo;
            }
            // B: 64 rows x 8 octets = 512 slots -> 1/thread (hi & lo)
            {
                int row = tid >> 3, oct = tid & 7;
                size_t src = (size_t)(n0 + row) * Ktot + kbase + oct * 8;
                *(u16x8*)&sBhi[row * PITCH + oct * 8] = *(const u16x8*)&WUthi[src];
                *(u16x8*)&sBlo[row * PITCH + oct * 8] = *(const u16x8*)&WUtlo[src];
            }
            __syncthreads();
            #pragma unroll
            for (int s = 0; s < 4; ++s) {              // 4x K16 per chunk
                const int o = s * 16;
                s8v ah = *(const s8v*)&sAhi[rowA + o];
                s8v al = *(const s8v*)&sAlo[rowA + o];
                s8v bh = *(const s8v*)&sBhi[rowB + o];
                s8v bl = *(const s8v*)&sBlo[rowB + o];
                acc = __builtin_amdgcn_mfma_f32_32x32x16_bf16(ah, bh, acc, 0, 0, 0);
                acc = __builtin_amdgcn_mfma_f32_32x32x16_bf16(al, bh, acc, 0, 0, 0);
                acc = __builtin_amdgcn_mfma_f32_32x32x16_bf16(ah, bl, acc, 0, 0, 0);
            }
            __syncthreads();
        }

        // C/D layout (verified m74/m101): col = lane&31, row = (reg&3) + 8*(reg>>2) + 4*(lane>>5)
        {
            float* Pk = P + (size_t)kt * Bsz * G4;
            const int mb = mq * 32 + 4 * (lane >> 5);
            #pragma unroll
            for (int r = 0; r < 16; ++r) {
                int m = mb + (r & 3) + 8 * (r >> 2);
                Pk[(size_t)m * G4 + n0 + nh * 32 + m31] = acc[r];
            }
        }
        grid.sync();

        // ---- pointwise phase: combine 4 K-partials, activations, state update ----
        float gf = bf_, gi = bi_, gg = bg_, go = bo_;
        #pragma unroll
        for (int s = 0; s < 4; ++s) {
            const float* Pb = P + (((size_t)(s * Bsz + pb)) << 12) + pj;
            gf += Pb[0];
            gi += Pb[1024];
            gg += Pb[2048];
            go += Pb[3072];
        }
        float f  = fsig(gf);
        float i_ = fsig(gi);
        float g  = ftanh(gg);
        float o  = fsig(go);
        c_reg = f * c_reg + i_ * g;
        float hn = o * ftanh(c_reg);
        hs_reg += hn;
        unsigned short hh = f2bf(hn);
        hhi[idx] = hh;
        hlo[idx] = f2bf(hn - bf2f(hh));
        if (t + 1 < Ssz && idx < Bsz * Isz) {
            int bb = idx >> 9, ii = idx & 511;
            float xv = x[((size_t)bb * Ssz + (t + 1)) * Isz + ii];
            unsigned short xh = f2bf(xv);
            xthi[idx] = xh;
            xtlo[idx] = f2bf(xv - bf2f(xh));
        }
        grid.sync();
    }

    out[idx] = hs_reg * (1.f / (float)Ssz);
}

extern "C" void kernel_launch(void* const* d_in, const int* in_sizes, int n_in,
                              void* d_out, int out_size, void* d_ws, size_t ws_size,
                              hipStream_t stream) {
    const float* x    = (const float*)d_in[0];
    const float* W    = (const float*)d_in[1];
    const float* U    = (const float*)d_in[2];
    const float* bias = (const float*)d_in[3];
    float* out = (float*)d_out;

    unsigned char* base = (unsigned char*)d_ws;
    // ws carve (~34.1 MB total)
    unsigned short* WUthi = (unsigned short*)(base);                       // 12,582,912 B
    unsigned short* WUtlo = (unsigned short*)(base + 12582912);            // 12,582,912 B
    float*          P     = (float*)(base + 25165824);                     //  8,388,608 B
    unsigned short* hhi   = (unsigned short*)(base + 33554432);            //    262,144 B
    unsigned short* hlo   = (unsigned short*)(base + 33816576);            //    262,144 B
    unsigned short* xthi  = (unsigned short*)(base + 34078720);            //    131,072 B
    unsigned short* xtlo  = (unsigned short*)(base + 34209792);            //    131,072 B

    conv_wu<<<dim3(G4 / 32, Ktot / 32), 256, 0, stream>>>(W, U, WUthi, WUtlo);

    void* args[] = {
        (void*)&WUthi, (void*)&WUtlo, (void*)&x, (void*)&bias, (void*)&P,
        (void*)&hhi, (void*)&hlo, (void*)&xthi, (void*)&xtlo, (void*)&out
    };
    hipLaunchCooperativeKernel((const void*)lstm_persist, dim3(256), dim3(512),
                               args, (unsigned)(SMEM_ELEMS * 2), stream);
}

// Round 2
// 25725.394 us; speedup vs baseline: 1.4816x; 1.4816x over previous
//
#include <hip/hip_runtime.h>
#include <cmath>

#define Bsz 128
#define Ssz 512
#define Isz 512
#define Hsz 1024
#define G4  4096
#define Ktot 1536   // I + H

typedef short s8v __attribute__((ext_vector_type(8)));        // 8 bf16 (4 VGPRs)
typedef unsigned short u16x8 __attribute__((ext_vector_type(8)));
typedef float f32x16 __attribute__((ext_vector_type(16)));

__device__ __forceinline__ unsigned short f2bf(float f) {
    unsigned u = __float_as_uint(f);
    u += 0x7fffu + ((u >> 16) & 1u);
    return (unsigned short)(u >> 16);
}
__device__ __forceinline__ float bf2f(unsigned short h) {
    return __uint_as_float(((unsigned)h) << 16);
}
__device__ __forceinline__ float fsig(float v) { return 1.f / (1.f + __expf(-v)); }
__device__ __forceinline__ float ftanh(float v) { return 2.f / (1.f + __expf(-2.f * v)) - 1.f; }

// ---- once per call: W,U -> transposed bf16 hi/lo planes, GATE-INTERLEAVED columns.
// dst row for orig column n (n = g*1024 + j): perm(n) = j*4 + g.
// A block of 64 dst rows = 16 hidden units x 4 gates -> pointwise is block-local.
__global__ __launch_bounds__(256) void conv_wu(const float* __restrict__ W,
                                               const float* __restrict__ U,
                                               unsigned short* __restrict__ WUthi,
                                               unsigned short* __restrict__ WUtlo) {
    __shared__ float tile[32][33];
    const int tx = threadIdx.x & 31, ty = threadIdx.x >> 5;
    const int nb = blockIdx.x * 32, kb = blockIdx.y * 32;
    #pragma unroll
    for (int r = 0; r < 4; ++r) {
        int k = kb + ty + r * 8;
        float v = (k < Isz) ? W[(size_t)k * G4 + nb + tx]
                            : U[(size_t)(k - Isz) * G4 + nb + tx];
        tile[ty + r * 8][tx] = v;
    }
    __syncthreads();
    #pragma unroll
    for (int r = 0; r < 4; ++r) {
        int nl = ty + r * 8;
        int n  = nb + nl;                        // orig column (tile never straddles a gate)
        int pn = ((n & 1023) << 2) | (n >> 10);  // j*4 + g
        float v = tile[tx][nl];
        unsigned short h = f2bf(v);
        size_t dst = (size_t)pn * Ktot + kb + tx;
        WUthi[dst] = h;
        WUtlo[dst] = f2bf(v - bf2f(h));
    }
}

// ---- once per call: zero state, split x[:,0,:]
__global__ __launch_bounds__(256) void lstm_init(const float* __restrict__ x,
                                                 float* __restrict__ c, float* __restrict__ hsum,
                                                 unsigned short* __restrict__ hhi, unsigned short* __restrict__ hlo,
                                                 unsigned short* __restrict__ xthi, unsigned short* __restrict__ xtlo) {
    int idx = blockIdx.x * 256 + threadIdx.x;   // 131072 threads
    c[idx] = 0.f; hsum[idx] = 0.f; hhi[idx] = 0; hlo[idx] = 0;
    if (idx < Bsz * Isz) {
        int b = idx >> 9, i = idx & 511;
        float xv = x[(size_t)b * Ssz * Isz + i];   // t = 0
        unsigned short h = f2bf(xv);
        xthi[idx] = h;
        xtlo[idx] = f2bf(xv - bf2f(h));
    }
}

// ---- per step, ONE kernel: full-K GEMM for 64 gate-columns + fused pointwise.
// grid = 64 blocks (one per 16 hidden units), 512 threads = 8 waves (M128 x N64 in 32x32 tiles)
#define PITCH 72          // 64 k + 8 pad (u16 elems); 144 B, 16B-aligned
#define A_HI 0
#define A_LO (128 * PITCH)
#define B_HI (2 * 128 * PITCH)
#define B_LO (2 * 128 * PITCH + 64 * PITCH)
#define SMEM_ELEMS (2 * 128 * PITCH + 2 * 64 * PITCH)   // 27648 u16 = 55296 B
#define LGP 68            // epilogue float pitch (bank-shifted)

__global__ __launch_bounds__(512) void lstm_step(
    const unsigned short* __restrict__ WUthi, const unsigned short* __restrict__ WUtlo,
    const unsigned short* __restrict__ xthi,  const unsigned short* __restrict__ xtlo,
    const unsigned short* __restrict__ hhi_in, const unsigned short* __restrict__ hlo_in,
    const float* __restrict__ bias, const float* __restrict__ x, int t,
    float* __restrict__ c_st, float* __restrict__ hsum,
    unsigned short* __restrict__ hhi, unsigned short* __restrict__ hlo,
    unsigned short* __restrict__ xthi_o, unsigned short* __restrict__ xtlo_o,
    float* __restrict__ out) {
    extern __shared__ unsigned short sm[];
    unsigned short* sAhi = sm + A_HI;
    unsigned short* sAlo = sm + A_LO;
    unsigned short* sBhi = sm + B_HI;
    unsigned short* sBlo = sm + B_LO;

    const int tid = threadIdx.x, lane = tid & 63, w = tid >> 6;
    const int bid = blockIdx.x;
    const int n0 = bid * 64;

    const int m31  = lane & 31;
    const int koct = (lane >> 5) << 3;                 // 0 or 8
    const int mq = w & 3, nh = w >> 2;                 // wave -> (M-tile, N-half)
    const int rowA = (mq * 32 + m31) * PITCH + koct;
    const int rowB = (nh * 32 + m31) * PITCH + koct;

    f32x16 acc;
    #pragma unroll
    for (int i = 0; i < 16; ++i) acc[i] = 0.f;

    for (int kc = 0; kc < 24; ++kc) {                  // 24 chunks of K=64 (full 1536)
        const int kbase = kc * 64;
        const bool isX = (kbase < Isz);                // chunks 0..7 = x, 8..23 = h
        // A: 128 rows x 8 octets = 1024 slots -> 2/thread (hi & lo)
        #pragma unroll
        for (int i = 0; i < 2; ++i) {
            int q = i * 512 + tid;
            int row = q >> 3, oct = q & 7;
            int kg = kbase + oct * 8;
            const unsigned short* shi;
            const unsigned short* slo;
            if (isX) { shi = xthi + row * Isz + kg;              slo = xtlo + row * Isz + kg; }
            else     { shi = hhi_in + row * Hsz + (kg - Isz);    slo = hlo_in + row * Hsz + (kg - Isz); }
            *(u16x8*)&sAhi[row * PITCH + oct * 8] = *(const u16x8*)shi;
            *(u16x8*)&sAlo[row * PITCH + oct * 8] = *(const u16x8*)slo;
        }
        // B: 64 rows x 8 octets = 512 slots -> 1/thread (hi & lo)
        {
            int row = tid >> 3, oct = tid & 7;
            size_t src = (size_t)(n0 + row) * Ktot + kbase + oct * 8;
            *(u16x8*)&sBhi[row * PITCH + oct * 8] = *(const u16x8*)&WUthi[src];
            *(u16x8*)&sBlo[row * PITCH + oct * 8] = *(const u16x8*)&WUtlo[src];
        }
        __syncthreads();
        #pragma unroll
        for (int s = 0; s < 4; ++s) {                  // 4x K16 per chunk
            const int o = s * 16;
            s8v ah = *(const s8v*)&sAhi[rowA + o];
            s8v al = *(const s8v*)&sAlo[rowA + o];
            s8v bh = *(const s8v*)&sBhi[rowB + o];
            s8v bl = *(const s8v*)&sBlo[rowB + o];
            acc = __builtin_amdgcn_mfma_f32_32x32x16_bf16(ah, bh, acc, 0, 0, 0);
            acc = __builtin_amdgcn_mfma_f32_32x32x16_bf16(al, bh, acc, 0, 0, 0);
            acc = __builtin_amdgcn_mfma_f32_32x32x16_bf16(ah, bl, acc, 0, 0, 0);
        }
        __syncthreads();
    }

    // ---- epilogue: bounce acc through LDS (reuse A region), then fused pointwise.
    // C/D layout (m74/m101): col = lane&31, row = (reg&3) + 8*(reg>>2) + 4*(lane>>5)
    float* Lg = (float*)sm;                            // [128][LGP] floats = 34816 B (< A region 36864 B)
    {
        const int colL = nh * 32 + m31;
        const int mb = mq * 32 + 4 * (lane >> 5);
        #pragma unroll
        for (int r = 0; r < 16; ++r) {
            int m = mb + (r & 3) + 8 * (r >> 2);
            Lg[m * LGP + colL] = acc[r];
        }
    }
    __syncthreads();

    {
        const int jl = tid & 15;                       // local hidden unit 0..15
        const int q  = tid >> 4;                       // 0..31
        const int j  = bid * 16 + jl;                  // global hidden unit
        const float bf_ = bias[j], bi_ = bias[1024 + j],
                    bg_ = bias[2048 + j], bo_ = bias[3072 + j];
        #pragma unroll
        for (int i = 0; i < 4; ++i) {
            int b = q + 32 * i;
            const float4 g4 = *(const float4*)&Lg[b * LGP + 4 * jl];  // (f,i,g,o) adjacent
            float f  = fsig(g4.x + bf_);
            float i_ = fsig(g4.y + bi_);
            float g  = ftanh(g4.z + bg_);
            float o  = fsig(g4.w + bo_);
            size_t sidx = (size_t)b * Hsz + j;
            float cn = f * c_st[sidx] + i_ * g;
            c_st[sidx] = cn;
            float hn = o * ftanh(cn);
            float hs = hsum[sidx] + hn;
            hsum[sidx] = hs;
            unsigned short hh = f2bf(hn);
            hhi[sidx] = hh;
            hlo[sidx] = f2bf(hn - bf2f(hh));
            if (t == Ssz - 1) out[sidx] = hs * (1.f / (float)Ssz);
        }
    }

    // stage next x slice (64 blocks x 512 threads = 32768 threads for 65536 elems)
    if (t + 1 < Ssz) {
        #pragma unroll
        for (int i = 0; i < 2; ++i) {
            int idx = bid * 512 + tid + i * 32768;
            int bb = idx >> 9, ii = idx & 511;
            float xv = x[((size_t)bb * Ssz + (t + 1)) * Isz + ii];
            unsigned short xh = f2bf(xv);
            xthi_o[idx] = xh;
            xtlo_o[idx] = f2bf(xv - bf2f(xh));
        }
    }
}

extern "C" void kernel_launch(void* const* d_in, const int* in_sizes, int n_in,
                              void* d_out, int out_size, void* d_ws, size_t ws_size,
                              hipStream_t stream) {
    const float* x    = (const float*)d_in[0];
    const float* W    = (const float*)d_in[1];
    const float* U    = (const float*)d_in[2];
    const float* bias = (const float*)d_in[3];
    float* out = (float*)d_out;

    unsigned char* base = (unsigned char*)d_ws;
    // ws carve (~27 MB total)
    unsigned short* WUthi = (unsigned short*)(base);                       // 12,582,912 B
    unsigned short* WUtlo = (unsigned short*)(base + 12582912);            // 12,582,912 B
    float*          c_st  = (float*)(base + 25165824);                     //    524,288 B
    float*          hsum  = (float*)(base + 25690112);                     //    524,288 B
    unsigned short* hhi   = (unsigned short*)(base + 26214400);            //    262,144 B
    unsigned short* hlo   = (unsigned short*)(base + 26476544);            //    262,144 B
    unsigned short* xthi  = (unsigned short*)(base + 26738688);            //    131,072 B
    unsigned short* xtlo  = (unsigned short*)(base + 26869760);            //    131,072 B

    conv_wu<<<dim3(G4 / 32, Ktot / 32), 256, 0, stream>>>(W, U, WUthi, WUtlo);
    lstm_init<<<(Bsz * Hsz) / 256, 256, 0, stream>>>(x, c_st, hsum, hhi, hlo, xthi, xtlo);

    for (int t = 0; t < Ssz; ++t) {
        lstm_step<<<64, 512, SMEM_ELEMS * 2, stream>>>(
            WUthi, WUtlo, xthi, xtlo, hhi, hlo, bias, x, t,
            c_st, hsum, hhi, hlo, xthi, xtlo, out);
    }
}

// Round 3
// 14813.515 us; speedup vs baseline: 2.5730x; 1.7366x over previous
//
#include <hip/hip_runtime.h>
#include <cmath>

#define Bsz 128
#define Ssz 512
#define Isz 512
#define Hsz 1024
#define G4  4096
#define Ktot 1536   // I + H
#define NT  32      // N-tiles of 128 cols
#define KT  8       // K-slices of 192
#define KSL 192

typedef short s8v __attribute__((ext_vector_type(8)));        // 8 bf16 (4 VGPRs)
typedef unsigned short u16x8 __attribute__((ext_vector_type(8)));
typedef float f32x16 __attribute__((ext_vector_type(16)));
typedef float f32x4  __attribute__((ext_vector_type(4)));

__device__ __forceinline__ unsigned short f2bf(float f) {
    unsigned u = __float_as_uint(f);
    u += 0x7fffu + ((u >> 16) & 1u);
    return (unsigned short)(u >> 16);
}
__device__ __forceinline__ float bf2f(unsigned short h) {
    return __uint_as_float(((unsigned)h) << 16);
}
__device__ __forceinline__ float fsig(float v) { return 1.f / (1.f + __expf(-v)); }
__device__ __forceinline__ float ftanh(float v) { return 2.f / (1.f + __expf(-2.f * v)) - 1.f; }

// ---- once per call: W,U -> transposed bf16 hi/lo planes, GATE-INTERLEAVED columns.
// dst row for orig column n (n = g*1024 + j): perm(n) = j*4 + g.
__global__ __launch_bounds__(256) void conv_wu(const float* __restrict__ W,
                                               const float* __restrict__ U,
                                               unsigned short* __restrict__ WUthi,
                                               unsigned short* __restrict__ WUtlo) {
    __shared__ float tile[32][33];
    const int tx = threadIdx.x & 31, ty = threadIdx.x >> 5;
    const int nb = blockIdx.x * 32, kb = blockIdx.y * 32;
    #pragma unroll
    for (int r = 0; r < 4; ++r) {
        int k = kb + ty + r * 8;
        float v = (k < Isz) ? W[(size_t)k * G4 + nb + tx]
                            : U[(size_t)(k - Isz) * G4 + nb + tx];
        tile[ty + r * 8][tx] = v;
    }
    __syncthreads();
    #pragma unroll
    for (int r = 0; r < 4; ++r) {
        int nl = ty + r * 8;
        int n  = nb + nl;                        // orig column (tile never straddles a gate)
        int pn = ((n & 1023) << 2) | (n >> 10);  // j*4 + g
        float v = tile[tx][nl];
        unsigned short h = f2bf(v);
        size_t dst = (size_t)pn * Ktot + kb + tx;
        WUthi[dst] = h;
        WUtlo[dst] = f2bf(v - bf2f(h));
    }
}

// ---- once per call: zero state/counters, permute bias, split x[:,0,:]
__global__ __launch_bounds__(256) void lstm_init(const float* __restrict__ x,
                                                 const float* __restrict__ bias,
                                                 float* __restrict__ c, float* __restrict__ hsum,
                                                 unsigned short* __restrict__ hhi0, unsigned short* __restrict__ hlo0,
                                                 unsigned short* __restrict__ xthi0, unsigned short* __restrict__ xtlo0,
                                                 float* __restrict__ biasP, unsigned* __restrict__ cnt) {
    int idx = blockIdx.x * 256 + threadIdx.x;   // 131072 threads
    c[idx] = 0.f; hsum[idx] = 0.f; hhi0[idx] = 0; hlo0[idx] = 0;
    if (idx < Bsz * Isz) {
        int b = idx >> 9, i = idx & 511;
        float xv = x[(size_t)b * Ssz * Isz + i];   // t = 0
        unsigned short h = f2bf(xv);
        xthi0[idx] = h;
        xtlo0[idx] = f2bf(xv - bf2f(h));
    }
    if (idx < G4)  biasP[idx] = bias[((idx & 3) << 10) | (idx >> 2)];  // biasP[j*4+g]
    if (idx < 1024) cnt[idx] = 0u;
}

// ---- per step, ONE kernel: split-K GEMM (256 blocks) + ticketed fused pointwise.
// grid = 256 blocks: kt = bid&7 (XCD-aligned K-slice), nt = bid>>3 (128 cols = 32 units).
#define PITCH 72          // 64 k + 8 pad (u16 elems); 144 B, bank-uniform
#define A_HI 0
#define A_LO (128 * PITCH)
#define B_HI (2 * 128 * PITCH)
#define B_LO (3 * 128 * PITCH)
#define SMEM_ELEMS (4 * 128 * PITCH)   // 36864 u16 = 73728 B

__global__ __launch_bounds__(512) void lstm_step(
    const unsigned short* __restrict__ WUthi, const unsigned short* __restrict__ WUtlo,
    const unsigned short* __restrict__ xthi,  const unsigned short* __restrict__ xtlo,
    const unsigned short* __restrict__ hhi_in, const unsigned short* __restrict__ hlo_in,
    const float* __restrict__ biasP, const float* __restrict__ x, int t,
    float* __restrict__ c_st, float* __restrict__ hsum,
    unsigned short* __restrict__ hhi_o, unsigned short* __restrict__ hlo_o,
    unsigned short* __restrict__ xthi_o, unsigned short* __restrict__ xtlo_o,
    float* __restrict__ P, unsigned* __restrict__ cnt,
    float* __restrict__ out) {
    extern __shared__ unsigned short sm[];
    unsigned short* sAhi = sm + A_HI;
    unsigned short* sAlo = sm + A_LO;
    unsigned short* sBhi = sm + B_HI;
    unsigned short* sBlo = sm + B_LO;

    const int tid = threadIdx.x, lane = tid & 63, w = tid >> 6;
    const int bid = blockIdx.x;
    const int kt = bid & 7, nt = bid >> 3;

    const int m31  = lane & 31;
    const int koct = (lane >> 5) << 3;                 // 0 or 8
    const int mq = w & 3, nh = w >> 2;                 // wave -> (M-tile, N-half)
    const int rowA  = (mq * 32 + m31) * PITCH + koct;
    const int rowB0 = (nh * 64 + m31) * PITCH + koct;
    const int rowB1 = rowB0 + 32 * PITCH;

    f32x16 acc0, acc1;
    #pragma unroll
    for (int i = 0; i < 16; ++i) { acc0[i] = 0.f; acc1[i] = 0.f; }

    for (int kc = 0; kc < 3; ++kc) {                   // 3 chunks of K=64 (slice K=192)
        const int kb = kt * KSL + kc * 64;
        const bool isX = (kb < Isz);                   // chunk never straddles k=512
        // A: 128 rows x 8 octets = 1024 slots -> 2/thread (hi & lo)
        #pragma unroll
        for (int i = 0; i < 2; ++i) {
            int q = i * 512 + tid;
            int row = q >> 3, oct = q & 7;
            int kg = kb + oct * 8;
            const unsigned short* shi;
            const unsigned short* slo;
            if (isX) { shi = xthi + row * Isz + kg;              slo = xtlo + row * Isz + kg; }
            else     { shi = hhi_in + row * Hsz + (kg - Isz);    slo = hlo_in + row * Hsz + (kg - Isz); }
            *(u16x8*)&sAhi[row * PITCH + oct * 8] = *(const u16x8*)shi;
            *(u16x8*)&sAlo[row * PITCH + oct * 8] = *(const u16x8*)slo;
        }
        // B: 128 rows x 8 octets = 1024 slots -> 2/thread (hi & lo)
        #pragma unroll
        for (int i = 0; i < 2; ++i) {
            int q = i * 512 + tid;
            int row = q >> 3, oct = q & 7;
            size_t src = (size_t)(nt * 128 + row) * Ktot + kb + oct * 8;
            *(u16x8*)&sBhi[row * PITCH + oct * 8] = *(const u16x8*)&WUthi[src];
            *(u16x8*)&sBlo[row * PITCH + oct * 8] = *(const u16x8*)&WUtlo[src];
        }
        __syncthreads();
        #pragma unroll
        for (int s = 0; s < 4; ++s) {                  // 4x K16 per chunk
            const int o = s * 16;
            s8v ah  = *(const s8v*)&sAhi[rowA + o];
            s8v al  = *(const s8v*)&sAlo[rowA + o];
            s8v b0h = *(const s8v*)&sBhi[rowB0 + o];
            s8v b0l = *(const s8v*)&sBlo[rowB0 + o];
            s8v b1h = *(const s8v*)&sBhi[rowB1 + o];
            s8v b1l = *(const s8v*)&sBlo[rowB1 + o];
            acc0 = __builtin_amdgcn_mfma_f32_32x32x16_bf16(ah, b0h, acc0, 0, 0, 0);
            acc1 = __builtin_amdgcn_mfma_f32_32x32x16_bf16(ah, b1h, acc1, 0, 0, 0);
            acc0 = __builtin_amdgcn_mfma_f32_32x32x16_bf16(al, b0h, acc0, 0, 0, 0);
            acc1 = __builtin_amdgcn_mfma_f32_32x32x16_bf16(al, b1h, acc1, 0, 0, 0);
            acc0 = __builtin_amdgcn_mfma_f32_32x32x16_bf16(ah, b0l, acc0, 0, 0, 0);
            acc1 = __builtin_amdgcn_mfma_f32_32x32x16_bf16(ah, b1l, acc1, 0, 0, 0);
        }
        __syncthreads();
    }

    // ---- store partial to P, LLC-direct (sc0 sc1 bypass: no L2 pollution, no wbl2 needed)
    // C/D layout (m74/m101): col = lane&31, row = (reg&3) + 8*(reg>>2) + 4*(lane>>5)
    {
        float* Ps = P + (size_t)(kt * NT + nt) * (Bsz * 128);
        const int mb = mq * 32 + 4 * (lane >> 5);
        const int c0 = nh * 64 + m31;
        #pragma unroll
        for (int r = 0; r < 16; ++r) {
            int m = mb + (r & 3) + 8 * (r >> 2);
            float* p0 = Ps + m * 128 + c0;
            float v0 = acc0[r], v1 = acc1[r];
            asm volatile("global_store_dword %0, %1, off sc0 sc1" :: "v"(p0), "v"(v0) : "memory");
            asm volatile("global_store_dword %0, %1, off sc0 sc1" :: "v"(p0 + 32), "v"(v1) : "memory");
        }
    }
    asm volatile("s_waitcnt vmcnt(0)" ::: "memory");
    __syncthreads();                                   // all waves' stores drained

    // ---- ticket: last of the 8 kt-blocks for this nt does the pointwise
    if (tid == 0) {
        unsigned old = __hip_atomic_fetch_add(&cnt[nt * 32], 1u,
                                              __ATOMIC_RELAXED, __HIP_MEMORY_SCOPE_AGENT);
        ((unsigned*)sm)[0] = (old == (unsigned)(KT * (t + 1) - 1)) ? 1u : 0u;
    }
    __syncthreads();
    if (((unsigned*)sm)[0] == 0u) return;

    // ---- reader: reduce 8 partials (bypass loads), activations, state update
    const float* Pn = P + (size_t)nt * (Bsz * 128);
    #pragma unroll 1
    for (int j4 = 0; j4 < 8; ++j4) {
        const int e = j4 * 2048 + tid * 4;             // [b][jl], jl 4-aligned = one unit
        f32x4 part[KT];
        #pragma unroll
        for (int k2 = 0; k2 < KT; ++k2) {
            const float* p = Pn + (size_t)k2 * (NT * Bsz * 128) + e;
            asm volatile("global_load_dwordx4 %0, %1, off sc0 sc1" : "=v"(part[k2]) : "v"(p));
        }
        asm volatile("s_waitcnt vmcnt(0)" ::: "memory");
        __builtin_amdgcn_sched_barrier(0);
        const int jl = e & 127, b = e >> 7;
        f32x4 bp = *(const f32x4*)&biasP[nt * 128 + jl];
        float gf = bp.x, gi = bp.y, gg = bp.z, go = bp.w;
        #pragma unroll
        for (int k2 = 0; k2 < KT; ++k2) {
            gf += part[k2][0]; gi += part[k2][1]; gg += part[k2][2]; go += part[k2][3];
        }
        float f  = fsig(gf);
        float i_ = fsig(gi);
        float g  = ftanh(gg);
        float o  = fsig(go);
        size_t sidx = (size_t)b * Hsz + nt * 32 + (jl >> 2);
        float cn = f * c_st[sidx] + i_ * g;
        c_st[sidx] = cn;
        float hn = o * ftanh(cn);
        float hs = hsum[sidx] + hn;
        hsum[sidx] = hs;
        unsigned short hh = f2bf(hn);
        hhi_o[sidx] = hh;
        hlo_o[sidx] = f2bf(hn - bf2f(hh));
        if (t == Ssz - 1) out[sidx] = hs * (1.f / (float)Ssz);
    }

    // ---- stage next x slice (32 reader blocks x 512 thr x 4 = 65536 elems)
    if (t + 1 < Ssz) {
        #pragma unroll
        for (int i = 0; i < 4; ++i) {
            int idx = nt * 2048 + i * 512 + tid;
            int bb = idx >> 9, ii = idx & 511;
            float xv = x[((size_t)bb * Ssz + (t + 1)) * Isz + ii];
            unsigned short xh = f2bf(xv);
            xthi_o[idx] = xh;
            xtlo_o[idx] = f2bf(xv - bf2f(xh));
        }
    }
}

extern "C" void kernel_launch(void* const* d_in, const int* in_sizes, int n_in,
                              void* d_out, int out_size, void* d_ws, size_t ws_size,
                              hipStream_t stream) {
    const float* x    = (const float*)d_in[0];
    const float* W    = (const float*)d_in[1];
    const float* U    = (const float*)d_in[2];
    const float* bias = (const float*)d_in[3];
    float* out = (float*)d_out;

    unsigned char* base = (unsigned char*)d_ws;
    // ws carve (~44.6 MB total)
    unsigned short* WUthi = (unsigned short*)(base);                       // 12,582,912 B
    unsigned short* WUtlo = (unsigned short*)(base + 12582912);            // 12,582,912 B
    float*          P     = (float*)(base + 25165824);                     // 16,777,216 B
    float*          c_st  = (float*)(base + 41943040);                     //    524,288 B
    float*          hsum  = (float*)(base + 42467328);                     //    524,288 B
    unsigned short* hh0   = (unsigned short*)(base + 42991616);            //    262,144 B
    unsigned short* hl0   = (unsigned short*)(base + 43253760);            //    262,144 B
    unsigned short* hh1   = (unsigned short*)(base + 43515904);            //    262,144 B
    unsigned short* hl1   = (unsigned short*)(base + 43778048);            //    262,144 B
    unsigned short* xh0   = (unsigned short*)(base + 44040192);            //    131,072 B
    unsigned short* xl0   = (unsigned short*)(base + 44171264);            //    131,072 B
    unsigned short* xh1   = (unsigned short*)(base + 44302336);            //    131,072 B
    unsigned short* xl1   = (unsigned short*)(base + 44433408);            //    131,072 B
    float*          biasP = (float*)(base + 44564480);                     //     16,384 B
    unsigned*       cnt   = (unsigned*)(base + 44580864);                  //      4,096 B

    unsigned short* xh[2] = {xh0, xh1};
    unsigned short* xl[2] = {xl0, xl1};
    unsigned short* hh[2] = {hh0, hh1};
    unsigned short* hl[2] = {hl0, hl1};

    conv_wu<<<dim3(G4 / 32, Ktot / 32), 256, 0, stream>>>(W, U, WUthi, WUtlo);
    lstm_init<<<(Bsz * Hsz) / 256, 256, 0, stream>>>(x, bias, c_st, hsum,
                                                     hh0, hl0, xh0, xl0, biasP, cnt);

    for (int t = 0; t < Ssz; ++t) {
        lstm_step<<<NT * KT, 512, SMEM_ELEMS * 2, stream>>>(
            WUthi, WUtlo, xh[t & 1], xl[t & 1], hh[t & 1], hl[t & 1],
            biasP, x, t, c_st, hsum,
            hh[(t + 1) & 1], hl[(t + 1) & 1], xh[(t + 1) & 1], xl[(t + 1) & 1],
            P, cnt, out);
    }
}

// Round 4
// 6465.073 us; speedup vs baseline: 5.8956x; 2.2913x over previous
//
#include <hip/hip_runtime.h>
#include <cmath>

#define Bsz 128
#define Ssz 512
#define Isz 512
#define Hsz 1024
#define G4  4096
#define Ktot 1536   // I + H
#define NT  64      // N-tiles of 64 cols (16 hidden units)
#define KT  4       // K-slices of 384
#define KSL 384

typedef short s8v __attribute__((ext_vector_type(8)));        // 8 bf16 (4 VGPRs)
typedef unsigned short u16x8 __attribute__((ext_vector_type(8)));
typedef float f32x16 __attribute__((ext_vector_type(16)));
typedef float f32x4  __attribute__((ext_vector_type(4)));

__device__ __forceinline__ unsigned short f2bf(float f) {
    unsigned u = __float_as_uint(f);
    u += 0x7fffu + ((u >> 16) & 1u);
    return (unsigned short)(u >> 16);
}
__device__ __forceinline__ float bf2f(unsigned short h) {
    return __uint_as_float(((unsigned)h) << 16);
}
__device__ __forceinline__ float fsig(float v) { return 1.f / (1.f + __expf(-v)); }
__device__ __forceinline__ float ftanh(float v) { return 2.f / (1.f + __expf(-2.f * v)) - 1.f; }

// ---- once per call: W,U -> transposed bf16 hi/lo planes, GATE-INTERLEAVED columns.
// dst row for orig column n (n = g*1024 + j): perm(n) = j*4 + g.
__global__ __launch_bounds__(256) void conv_wu(const float* __restrict__ W,
                                               const float* __restrict__ U,
                                               unsigned short* __restrict__ WUthi,
                                               unsigned short* __restrict__ WUtlo) {
    __shared__ float tile[32][33];
    const int tx = threadIdx.x & 31, ty = threadIdx.x >> 5;
    const int nb = blockIdx.x * 32, kb = blockIdx.y * 32;
    #pragma unroll
    for (int r = 0; r < 4; ++r) {
        int k = kb + ty + r * 8;
        float v = (k < Isz) ? W[(size_t)k * G4 + nb + tx]
                            : U[(size_t)(k - Isz) * G4 + nb + tx];
        tile[ty + r * 8][tx] = v;
    }
    __syncthreads();
    #pragma unroll
    for (int r = 0; r < 4; ++r) {
        int nl = ty + r * 8;
        int n  = nb + nl;                        // orig column (tile never straddles a gate)
        int pn = ((n & 1023) << 2) | (n >> 10);  // j*4 + g
        float v = tile[tx][nl];
        unsigned short h = f2bf(v);
        size_t dst = (size_t)pn * Ktot + kb + tx;
        WUthi[dst] = h;
        WUtlo[dst] = f2bf(v - bf2f(h));
    }
}

// ---- once per call: zero state/counters, permute bias, split x[:,0,:]
__global__ __launch_bounds__(256) void lstm_init(const float* __restrict__ x,
                                                 const float* __restrict__ bias,
                                                 float* __restrict__ c, float* __restrict__ hsum,
                                                 unsigned short* __restrict__ hhi0, unsigned short* __restrict__ hlo0,
                                                 unsigned short* __restrict__ xthi0, unsigned short* __restrict__ xtlo0,
                                                 float* __restrict__ biasP, unsigned* __restrict__ cnt) {
    int idx = blockIdx.x * 256 + threadIdx.x;   // 131072 threads
    c[idx] = 0.f; hsum[idx] = 0.f; hhi0[idx] = 0; hlo0[idx] = 0;
    if (idx < Bsz * Isz) {
        int b = idx >> 9, i = idx & 511;
        float xv = x[(size_t)b * Ssz * Isz + i];   // t = 0
        unsigned short h = f2bf(xv);
        xthi0[idx] = h;
        xtlo0[idx] = f2bf(xv - bf2f(h));
    }
    if (idx < G4)  biasP[idx] = bias[((idx & 3) << 10) | (idx >> 2)];  // biasP[j*4+g]
    if (idx < 2048) cnt[idx] = 0u;
}

// ---- per step, ONE kernel: split-K GEMM + spin-grouped fused pointwise.
// grid = 256 blocks: nt = bid&63 (64-col tile), kt = bid>>6 (K-slice of 384).
// All 4 kt-blocks of a group land on XCD nt%8 if bid->XCD is %8 round-robin (perf
// only); correctness uses sc0 sc1 (LLC-level) for ALL cross-block traffic.
#define PITCH 72          // 64 k + 8 pad (u16 elems); 144 B, bank-uniform
#define A_HI 0
#define A_LO (128 * PITCH)
#define B_HI (2 * 128 * PITCH)
#define B_LO (2 * 128 * PITCH + 64 * PITCH)
#define SMEM_ELEMS (2 * 128 * PITCH + 2 * 64 * PITCH)   // 27648 u16 = 55296 B

__global__ __launch_bounds__(512) void lstm_step(
    const unsigned short* __restrict__ WUthi, const unsigned short* __restrict__ WUtlo,
    const unsigned short* __restrict__ xthi,  const unsigned short* __restrict__ xtlo,
    const unsigned short* __restrict__ hhi_in, const unsigned short* __restrict__ hlo_in,
    const float* __restrict__ biasP, const float* __restrict__ x, int t,
    float* __restrict__ c_st, float* __restrict__ hsum,
    unsigned short* __restrict__ hhi_o, unsigned short* __restrict__ hlo_o,
    unsigned short* __restrict__ xthi_o, unsigned short* __restrict__ xtlo_o,
    float* __restrict__ P, unsigned* __restrict__ cnt,
    float* __restrict__ out) {
    extern __shared__ unsigned short sm[];
    unsigned short* sAhi = sm + A_HI;
    unsigned short* sAlo = sm + A_LO;
    unsigned short* sBhi = sm + B_HI;
    unsigned short* sBlo = sm + B_LO;

    const int tid = threadIdx.x, lane = tid & 63, w = tid >> 6;
    const int bid = blockIdx.x;
    const int nt = bid & 63, kt = bid >> 6;

    const int m31  = lane & 31;
    const int koct = (lane >> 5) << 3;                 // 0 or 8
    const int mq = w & 3, nh = w >> 2;                 // 8 waves = 4 mq x 2 nh, tile 32x32
    const int rowA = (mq * 32 + m31) * PITCH + koct;
    const int rowB = (nh * 32 + m31) * PITCH + koct;

    // staging slots: A rows arow & arow+64, B row arow (0..63); oct = aoct
    const int arow = tid >> 3, aoct = tid & 7;
    const int awr0 = arow * PITCH + aoct * 8;
    const int awr1 = (arow + 64) * PITCH + aoct * 8;

    f32x16 acc;
    #pragma unroll
    for (int i = 0; i < 16; ++i) acc[i] = 0.f;

    u16x8 rAh0, rAl0, rAh1, rAl1, rBh, rBl;
#define LOADCHUNK(KC) { \
        const int kb_ = kt * KSL + (KC) * 64; \
        const int kg_ = kb_ + aoct * 8; \
        if (kb_ < Isz) { \
            const size_t o0 = (size_t)arow * Isz + kg_, o1 = (size_t)(arow + 64) * Isz + kg_; \
            rAh0 = *(const u16x8*)&xthi[o0]; rAl0 = *(const u16x8*)&xtlo[o0]; \
            rAh1 = *(const u16x8*)&xthi[o1]; rAl1 = *(const u16x8*)&xtlo[o1]; \
        } else { \
            const size_t o0 = (size_t)arow * Hsz + (kg_ - Isz), o1 = (size_t)(arow + 64) * Hsz + (kg_ - Isz); \
            rAh0 = *(const u16x8*)&hhi_in[o0]; rAl0 = *(const u16x8*)&hlo_in[o0]; \
            rAh1 = *(const u16x8*)&hhi_in[o1]; rAl1 = *(const u16x8*)&hlo_in[o1]; \
        } \
        const size_t ob_ = (size_t)(nt * 64 + arow) * Ktot + kg_; \
        rBh = *(const u16x8*)&WUthi[ob_]; rBl = *(const u16x8*)&WUtlo[ob_]; \
    }

    LOADCHUNK(0);
    #pragma unroll
    for (int kc = 0; kc < 6; ++kc) {                   // 6 chunks of K=64 (slice K=384)
        __syncthreads();                               // LDS free (prev compute done)
        *(u16x8*)&sAhi[awr0] = rAh0;
        *(u16x8*)&sAlo[awr0] = rAl0;
        *(u16x8*)&sAhi[awr1] = rAh1;
        *(u16x8*)&sAlo[awr1] = rAl1;
        *(u16x8*)&sBhi[awr0] = rBh;
        *(u16x8*)&sBlo[awr0] = rBl;
        if (kc < 5) LOADCHUNK(kc + 1);                 // next-chunk loads fly under MFMA
        __syncthreads();
        #pragma unroll
        for (int s = 0; s < 4; ++s) {                  // 4x K16 per chunk
            const int o = s * 16;
            s8v ah = *(const s8v*)&sAhi[rowA + o];
            s8v al = *(const s8v*)&sAlo[rowA + o];
            s8v bh = *(const s8v*)&sBhi[rowB + o];
            s8v bl = *(const s8v*)&sBlo[rowB + o];
            acc = __builtin_amdgcn_mfma_f32_32x32x16_bf16(ah, bh, acc, 0, 0, 0);
            acc = __builtin_amdgcn_mfma_f32_32x32x16_bf16(al, bh, acc, 0, 0, 0);
            acc = __builtin_amdgcn_mfma_f32_32x32x16_bf16(ah, bl, acc, 0, 0, 0);
        }
    }
#undef LOADCHUNK

    // ---- store partial to P, LLC-level (sc0 sc1: XCD-mapping-independent)
    // C/D layout (m74/m101): col = lane&31, row = (reg&3) + 8*(reg>>2) + 4*(lane>>5)
    {
        float* Ps = P + (size_t)(kt * NT + nt) * (Bsz * 64);
        const int mb = mq * 32 + 4 * (lane >> 5);
        const int c0 = nh * 32 + m31;
        #pragma unroll
        for (int r = 0; r < 16; ++r) {
            int m = mb + (r & 3) + 8 * (r >> 2);
            float* p0 = Ps + m * 64 + c0;
            float v0 = acc[r];
            asm volatile("global_store_dword %0, %1, off sc0 sc1" :: "v"(p0), "v"(v0) : "memory");
        }
    }

    // ---- stage next x slice (independent of P; overlaps the spin)
    if (t + 1 < Ssz && tid < 256) {
        int idx = bid * 256 + tid;                     // 65536 elems
        int bb = idx >> 9, ii = idx & 511;
        float xv = x[((size_t)bb * Ssz + (t + 1)) * Isz + ii];
        unsigned short xh = f2bf(xv);
        xthi_o[idx] = xh;
        xtlo_o[idx] = f2bf(xv - bf2f(xh));
    }

    __syncthreads();                                   // all waves drain vmcnt before ticket

    // ---- ticket + spin: group = 4 kt-blocks of this nt; all blocks co-resident (grid=256=#CU)
    if (tid == 0) {
        unsigned* cp = &cnt[nt * 32];
        unsigned one = 1u;
        asm volatile("s_waitcnt vmcnt(0) lgkmcnt(0)" ::: "memory");
        asm volatile("global_atomic_add %0, %1, off sc1" :: "v"(cp), "v"(one) : "memory");
        const unsigned target = (unsigned)(KT * (t + 1));   // cumulative, no reset needed
        unsigned v;
        do {
            __builtin_amdgcn_s_sleep(1);
            asm volatile("global_load_dword %0, %1, off sc0 sc1\n\ts_waitcnt vmcnt(0)"
                         : "=v"(v) : "v"(cp) : "memory");
        } while (v < target);
    }
    __syncthreads();

    // ---- all 256 blocks reduce: block kt handles b in [kt*32, kt*32+32) of its nt cols
    {
        const int jl = tid & 15;                       // local hidden unit 0..15
        const int brow = kt * 32 + (tid >> 4);         // 32 b-rows per block
        const int j = nt * 16 + jl;
        const float* Pb = P + ((size_t)nt * Bsz + brow) * 64 + jl * 4;
        const size_t kstride = (size_t)NT * Bsz * 64;  // 524288 floats
        f32x4 p0, p1, p2, p3;
        asm volatile("global_load_dwordx4 %0, %1, off sc0 sc1" : "=v"(p0) : "v"(Pb));
        asm volatile("global_load_dwordx4 %0, %1, off sc0 sc1" : "=v"(p1) : "v"(Pb + kstride));
        asm volatile("global_load_dwordx4 %0, %1, off sc0 sc1" : "=v"(p2) : "v"(Pb + 2 * kstride));
        asm volatile("global_load_dwordx4 %0, %1, off sc0 sc1" : "=v"(p3) : "v"(Pb + 3 * kstride));
        asm volatile("s_waitcnt vmcnt(0)" ::: "memory");
        __builtin_amdgcn_sched_barrier(0);
        f32x4 bp = *(const f32x4*)&biasP[(size_t)j * 4];
        float gf = bp.x + p0[0] + p1[0] + p2[0] + p3[0];
        float gi = bp.y + p0[1] + p1[1] + p2[1] + p3[1];
        float gg = bp.z + p0[2] + p1[2] + p2[2] + p3[2];
        float go = bp.w + p0[3] + p1[3] + p2[3] + p3[3];
        float f  = fsig(gf);
        float i_ = fsig(gi);
        float g  = ftanh(gg);
        float o  = fsig(go);
        size_t sidx = (size_t)brow * Hsz + j;
        float cn = f * c_st[sidx] + i_ * g;
        c_st[sidx] = cn;
        float hn = o * ftanh(cn);
        float hs = hsum[sidx] + hn;
        hsum[sidx] = hs;
        unsigned short hh = f2bf(hn);
        hhi_o[sidx] = hh;
        hlo_o[sidx] = f2bf(hn - bf2f(hh));
        if (t == Ssz - 1) out[sidx] = hs * (1.f / (float)Ssz);
    }
}

extern "C" void kernel_launch(void* const* d_in, const int* in_sizes, int n_in,
                              void* d_out, int out_size, void* d_ws, size_t ws_size,
                              hipStream_t stream) {
    const float* x    = (const float*)d_in[0];
    const float* W    = (const float*)d_in[1];
    const float* U    = (const float*)d_in[2];
    const float* bias = (const float*)d_in[3];
    float* out = (float*)d_out;

    unsigned char* base = (unsigned char*)d_ws;
    // ws carve (~36.3 MB total)
    unsigned short* WUthi = (unsigned short*)(base);                       // 12,582,912 B
    unsigned short* WUtlo = (unsigned short*)(base + 12582912);            // 12,582,912 B
    float*          P     = (float*)(base + 25165824);                     //  8,388,608 B
    float*          c_st  = (float*)(base + 33554432);                     //    524,288 B
    float*          hsum  = (float*)(base + 34078720);                     //    524,288 B
    unsigned short* hh0   = (unsigned short*)(base + 34603008);            //    262,144 B
    unsigned short* hl0   = (unsigned short*)(base + 34865152);            //    262,144 B
    unsigned short* hh1   = (unsigned short*)(base + 35127296);            //    262,144 B
    unsigned short* hl1   = (unsigned short*)(base + 35389440);            //    262,144 B
    unsigned short* xh0   = (unsigned short*)(base + 35651584);            //    131,072 B
    unsigned short* xl0   = (unsigned short*)(base + 35782656);            //    131,072 B
    unsigned short* xh1   = (unsigned short*)(base + 35913728);            //    131,072 B
    unsigned short* xl1   = (unsigned short*)(base + 36044800);            //    131,072 B
    float*          biasP = (float*)(base + 36175872);                     //     16,384 B
    unsigned*       cnt   = (unsigned*)(base + 36192256);                  //      8,192 B

    unsigned short* xh[2] = {xh0, xh1};
    unsigned short* xl[2] = {xl0, xl1};
    unsigned short* hh[2] = {hh0, hh1};
    unsigned short* hl[2] = {hl0, hl1};

    conv_wu<<<dim3(G4 / 32, Ktot / 32), 256, 0, stream>>>(W, U, WUthi, WUtlo);
    lstm_init<<<(Bsz * Hsz) / 256, 256, 0, stream>>>(x, bias, c_st, hsum,
                                                     hh0, hl0, xh0, xl0, biasP, cnt);

    for (int t = 0; t < Ssz; ++t) {
        lstm_step<<<NT * KT, 512, SMEM_ELEMS * 2, stream>>>(
            WUthi, WUtlo, xh[t & 1], xl[t & 1], hh[t & 1], hl[t & 1],
            biasP, x, t, c_st, hsum,
            hh[(t + 1) & 1], hl[(t + 1) & 1], xh[(t + 1) & 1], xl[(t + 1) & 1],
            P, cnt, out);
    }
}